// Round 6
// baseline (527.257 us; speedup 1.0000x reference)
//
#include <hip/hip_runtime.h>
#include <stdint.h>

#define NUM_NODES 17185
#define DD 6
#define FEATS (NUM_NODES * DD)   // 103110
#define BATCH 256
#define EPS 1e-5f

#define NC 256   // nodes per block (== threads, 1 node/thread)
#define BC 8     // batch rows per block (best measured)
#define NCHUNK ((NUM_NODES + NC - 1) / NC)   // 68
#define NBLOCKS (NCHUNK * (BATCH / BC))      // 2176

// Module-scope partials (d_ws unused; fills proved unconditional in R4).
// Every slot written before read within each launch -> no stale-state risk.
__device__ float g_pm[NCHUNK * 256];
__device__ float g_pc[NCHUNK];
__device__ int   g_cnt = 0;   // last-block-done counter; self-resets each launch

// NOTE: plain __launch_bounds__(NC). R5 proved that adding a min-waves/EU arg
// forces VGPR=40 -> full spill of wreg[36] -> 395us kernel. Never constrain
// registers on this kernel.
__global__ __launch_bounds__(NC) void main_kernel(
    const float* __restrict__ data, const float* __restrict__ wb, const float* __restrict__ bb,
    const float* __restrict__ gamma, const float* __restrict__ var, const float* __restrict__ fcw,
    const float* __restrict__ beta, const float* __restrict__ mean,
    const float* __restrict__ fcb, const float* __restrict__ bnfg,
    const float* __restrict__ bnfb, const float* __restrict__ bnfm,
    const float* __restrict__ bnfv, float* __restrict__ out) {

    const int tid = threadIdx.x;
    const int n = blockIdx.x * NC + tid;
    const bool valid = (n < NUM_NODES);

    float wreg[36], bias[6], a[6];
    #pragma unroll
    for (int k = 0; k < 36; k++) wreg[k] = 0.f;
    #pragma unroll
    for (int k = 0; k < 6; k++) { bias[k] = 0.f; a[k] = 0.f; }

    float cnode = 0.f;   // per-node contribution to the BN constant (only y==0 blocks)

    if (valid) {
        const float4* wp = (const float4*)(wb + (size_t)n * 36);   // 144B stride, 16-aligned
        #pragma unroll
        for (int k = 0; k < 9; k++) {
            float4 v = wp[k];
            wreg[4*k] = v.x; wreg[4*k+1] = v.y; wreg[4*k+2] = v.z; wreg[4*k+3] = v.w;
        }
        const float2* bp = (const float2*)(bb + (size_t)n * 6);
        #pragma unroll
        for (int k = 0; k < 3; k++) { float2 v = bp[k]; bias[2*k] = v.x; bias[2*k+1] = v.y; }
        const int f0 = n * 6;
        const float2* gp = (const float2*)(gamma + f0);
        const float2* vp = (const float2*)(var + f0);
        const float2* fp = (const float2*)(fcw + f0);
        float fw[6];
        #pragma unroll
        for (int k = 0; k < 3; k++) {
            float2 g = gp[k], v = vp[k], f = fp[k];
            fw[2*k] = f.x; fw[2*k+1] = f.y;
            a[2*k]   = g.x * rsqrtf(v.x + EPS) * f.x;
            a[2*k+1] = g.y * rsqrtf(v.y + EPS) * f.y;
        }
        if (blockIdx.y == 0) {
            const float2* bep = (const float2*)(beta + f0);
            const float2* mp  = (const float2*)(mean + f0);
            #pragma unroll
            for (int k = 0; k < 3; k++) {
                float2 be = bep[k], m = mp[k];
                cnode += be.x * fw[2*k]   - m.x * a[2*k];
                cnode += be.y * fw[2*k+1] - m.y * a[2*k+1];
            }
        }
    }

    const int b0 = blockIdx.y * BC;
    float acc[BC];
    #pragma unroll
    for (int r = 0; r < BC; r++) acc[r] = 0.f;

    if (valid) {
        const float2* xbase = (const float2*)(data + (size_t)b0 * FEATS + (size_t)n * 6);
        #pragma unroll
        for (int r = 0; r < BC; r++) {
            const float2* xp = xbase + (size_t)r * (FEATS / 2);
            float2 u0 = xp[0], u1 = xp[1], u2 = xp[2];
            float x0 = u0.x, x1 = u0.y, x2 = u1.x, x3 = u1.y, x4 = u2.x, x5 = u2.y;
            #pragma unroll
            for (int o = 0; o < 6; o++) {
                float s = bias[o];
                s = fmaf(x0, wreg[o*6+0], s);
                s = fmaf(x1, wreg[o*6+1], s);
                s = fmaf(x2, wreg[o*6+2], s);
                s = fmaf(x3, wreg[o*6+3], s);
                s = fmaf(x4, wreg[o*6+4], s);
                s = fmaf(x5, wreg[o*6+5], s);
                acc[r] = fmaf(fmaxf(s, 0.f), a[o], acc[r]);
            }
        }
    }

    // Block reduction: BC independent 6-deep shuffle chains.
    __shared__ float red[4][BC];
    __shared__ float credd[4];
    __shared__ int   s_last;
    #pragma unroll
    for (int r = 0; r < BC; r++) {
        float v = acc[r];
        #pragma unroll
        for (int off = 32; off; off >>= 1) v += __shfl_down(v, off);
        if ((tid & 63) == 0) red[tid >> 6][r] = v;
    }

    if (blockIdx.y == 0) {
        float v = cnode;
        #pragma unroll
        for (int off = 32; off; off >>= 1) v += __shfl_down(v, off);
        if ((tid & 63) == 0) credd[tid >> 6] = v;
        __syncthreads();
        if (tid == 0) g_pc[blockIdx.x] = credd[0] + credd[1] + credd[2] + credd[3];
    } else {
        __syncthreads();
    }

    if (tid < BC) {
        float s = red[0][tid] + red[1][tid] + red[2][tid] + red[3][tid];
        g_pm[blockIdx.x * 256 + b0 + tid] = s;   // chunk-major
    }

    // ---- last-block-done: fold the old final_kernel into the tail ----
    __threadfence();            // release: my pm/pc writes -> device scope
    __syncthreads();            // all lanes' writes issued & fenced
    if (tid == 0) {
        int old = atomicAdd(&g_cnt, 1);          // device-scope
        s_last = (old == NBLOCKS - 1);
    }
    __syncthreads();
    if (!s_last) return;

    __threadfence();            // acquire: see all other blocks' pm/pc

    float c = (tid < NCHUNK) ? g_pc[tid] : 0.f;
    #pragma unroll
    for (int off = 32; off; off >>= 1) c += __shfl_down(c, off);
    __shared__ float fred[4];
    if ((tid & 63) == 0) fred[tid >> 6] = c;
    __syncthreads();
    const float c_sum = fred[0] + fred[1] + fred[2] + fred[3];

    float y = 0.f;
    #pragma unroll 4
    for (int ch = 0; ch < NCHUNK; ch++) y += g_pm[ch * 256 + tid];   // coalesced

    y += c_sum + fcb[0];
    float sc = bnfg[0] * rsqrtf(bnfv[0] + EPS);
    float z = (y - bnfm[0]) * sc + bnfb[0];
    out[tid] = 1.f / (1.f + expf(-z));

    if (tid == 0) g_cnt = 0;    // reset for next graph replay
}

extern "C" void kernel_launch(void* const* d_in, const int* in_sizes, int n_in,
                              void* d_out, int out_size, void* d_ws, size_t ws_size,
                              hipStream_t stream) {
    const float* data  = (const float*)d_in[0];
    const float* wb    = (const float*)d_in[1];
    const float* bb    = (const float*)d_in[2];
    const float* gamma = (const float*)d_in[3];
    const float* beta  = (const float*)d_in[4];
    const float* mean  = (const float*)d_in[5];
    const float* var   = (const float*)d_in[6];
    const float* fcw   = (const float*)d_in[7];
    const float* fcb   = (const float*)d_in[8];
    const float* bnfg  = (const float*)d_in[9];
    const float* bnfb  = (const float*)d_in[10];
    const float* bnfm  = (const float*)d_in[11];
    const float* bnfv  = (const float*)d_in[12];
    (void)d_ws; (void)ws_size;   // workspace intentionally unused (fills are unconditional)

    dim3 grid(NCHUNK, BATCH / BC);            // (68, 32) = 2176 blocks
    main_kernel<<<grid, NC, 0, stream>>>(data, wb, bb, gamma, var, fcw, beta, mean,
                                         fcb, bnfg, bnfb, bnfm, bnfv, (float*)d_out);
}

// Round 7
// 209.034 us; speedup vs baseline: 2.5224x; 2.5224x over previous
//
#include <hip/hip_runtime.h>
#include <stdint.h>

#define NUM_NODES 17185
#define DD 6
#define FEATS (NUM_NODES * DD)   // 103110
#define BATCH 256
#define EPS 1e-5f

#define NC 256   // nodes per block
#define NT 512   // threads per block: 2 threads per node (output-split)
#define BC 8     // batch rows per block (best measured)
#define NCHUNK ((NUM_NODES + NC - 1) / NC)   // 68

// Module-scope partials (d_ws unused; fills proved unconditional in R4).
// Every slot written before read within each launch -> no stale-state risk.
__device__ float g_pm[NCHUNK * 256];
__device__ float g_pc[NCHUNK];

// R5/R6 lesson: never add a min-waves/EU launch-bounds arg (forces spill), and
// don't fuse the final reduction into this kernel (fusion tail alone causes
// a capped-VGPR spill regime: VGPR=60, 399us). Two plain kernels.
__global__ __launch_bounds__(NT) void main_kernel(
    const float* __restrict__ data, const float* __restrict__ wb, const float* __restrict__ bb,
    const float* __restrict__ gamma, const float* __restrict__ var, const float* __restrict__ fcw,
    const float* __restrict__ beta, const float* __restrict__ mean) {

    const int tid = threadIdx.x;
    const int nl  = tid & 255;        // node lane within chunk
    const int h   = tid >> 8;         // output half: 0 -> o=0..2, 1 -> o=3..5
    const int n   = blockIdx.x * NC + nl;
    const bool valid = (n < NUM_NODES);

    // Per-half state: 3 output rows of W (18), bias (3), a (3).
    float wreg[18], bias[3], a3[3];
    #pragma unroll
    for (int k = 0; k < 18; k++) wreg[k] = 0.f;
    #pragma unroll
    for (int k = 0; k < 3; k++) { bias[k] = 0.f; a3[k] = 0.f; }

    float cnode = 0.f;   // contribution to BN constant (y==0 blocks only)

    if (valid) {
        // W rows h*3..h*3+2: 18 floats at byte offset n*144 + h*72 (8-aligned)
        const float2* wp = (const float2*)(wb + (size_t)n * 36 + h * 18);
        #pragma unroll
        for (int k = 0; k < 9; k++) {
            float2 v = wp[k];
            wreg[2*k] = v.x; wreg[2*k+1] = v.y;
        }
        const int f0 = n * 6 + h * 3;
        #pragma unroll
        for (int j = 0; j < 3; j++) {
            bias[j] = bb[f0 + j];
            float fw = fcw[f0 + j];
            float aj = gamma[f0 + j] * rsqrtf(var[f0 + j] + EPS) * fw;
            a3[j] = aj;
            if (blockIdx.y == 0)
                cnode += beta[f0 + j] * fw - mean[f0 + j] * aj;
        }
    }

    const int b0 = blockIdx.y * BC;
    float acc[BC];
    #pragma unroll
    for (int r = 0; r < BC; r++) acc[r] = 0.f;

    if (valid) {
        const float2* xbase = (const float2*)(data + (size_t)b0 * FEATS + (size_t)n * 6);
        #pragma unroll
        for (int r = 0; r < BC; r++) {
            const float2* xp = xbase + (size_t)r * (FEATS / 2);
            float2 u0 = xp[0], u1 = xp[1], u2 = xp[2];   // same lines as other half -> L1 hit
            float x0 = u0.x, x1 = u0.y, x2 = u1.x, x3 = u1.y, x4 = u2.x, x5 = u2.y;
            #pragma unroll
            for (int j = 0; j < 3; j++) {
                float s = bias[j];
                s = fmaf(x0, wreg[j*6+0], s);
                s = fmaf(x1, wreg[j*6+1], s);
                s = fmaf(x2, wreg[j*6+2], s);
                s = fmaf(x3, wreg[j*6+3], s);
                s = fmaf(x4, wreg[j*6+4], s);
                s = fmaf(x5, wreg[j*6+5], s);
                acc[r] = fmaf(fmaxf(s, 0.f), a3[j], acc[r]);
            }
        }
    }

    // Block reduction: 8 waves, BC shuffle chains each.
    __shared__ float red[8][BC];
    const int w = tid >> 6;
    #pragma unroll
    for (int r = 0; r < BC; r++) {
        float v = acc[r];
        #pragma unroll
        for (int off = 32; off; off >>= 1) v += __shfl_down(v, off);
        if ((tid & 63) == 0) red[w][r] = v;
    }

    if (blockIdx.y == 0) {
        float v = cnode;
        #pragma unroll
        for (int off = 32; off; off >>= 1) v += __shfl_down(v, off);
        __shared__ float credd[8];
        if ((tid & 63) == 0) credd[w] = v;
        __syncthreads();
        if (tid == 0) {
            float s = 0.f;
            #pragma unroll
            for (int k = 0; k < 8; k++) s += credd[k];
            g_pc[blockIdx.x] = s;
        }
    } else {
        __syncthreads();
    }

    if (tid < BC) {
        float s = 0.f;
        #pragma unroll
        for (int k = 0; k < 8; k++) s += red[k][tid];
        g_pm[blockIdx.x * 256 + b0 + tid] = s;   // chunk-major for coalesced final read
    }
}

__global__ __launch_bounds__(256) void final_kernel(
    const float* __restrict__ fcb, const float* __restrict__ bnfg,
    const float* __restrict__ bnfb, const float* __restrict__ bnfm,
    const float* __restrict__ bnfv, float* __restrict__ out) {
    const int b = threadIdx.x;

    float c = (b < NCHUNK) ? g_pc[b] : 0.f;
    #pragma unroll
    for (int off = 32; off; off >>= 1) c += __shfl_down(c, off);
    __shared__ float red[4];
    if ((b & 63) == 0) red[b >> 6] = c;
    __syncthreads();
    const float c_sum = red[0] + red[1] + red[2] + red[3];

    float y = 0.f;
    #pragma unroll 4
    for (int ch = 0; ch < NCHUNK; ch++) y += g_pm[ch * 256 + b];   // coalesced

    y += c_sum + fcb[0];
    float sc = bnfg[0] * rsqrtf(bnfv[0] + EPS);
    float z = (y - bnfm[0]) * sc + bnfb[0];
    out[b] = 1.f / (1.f + expf(-z));
}

extern "C" void kernel_launch(void* const* d_in, const int* in_sizes, int n_in,
                              void* d_out, int out_size, void* d_ws, size_t ws_size,
                              hipStream_t stream) {
    const float* data  = (const float*)d_in[0];
    const float* wb    = (const float*)d_in[1];
    const float* bb    = (const float*)d_in[2];
    const float* gamma = (const float*)d_in[3];
    const float* beta  = (const float*)d_in[4];
    const float* mean  = (const float*)d_in[5];
    const float* var   = (const float*)d_in[6];
    const float* fcw   = (const float*)d_in[7];
    const float* fcb   = (const float*)d_in[8];
    const float* bnfg  = (const float*)d_in[9];
    const float* bnfb  = (const float*)d_in[10];
    const float* bnfm  = (const float*)d_in[11];
    const float* bnfv  = (const float*)d_in[12];
    (void)d_ws; (void)ws_size;   // workspace intentionally unused (fills are unconditional)

    dim3 grid(NCHUNK, BATCH / BC);            // (68, 32) = 2176 blocks, 512 threads each
    main_kernel<<<grid, NT, 0, stream>>>(data, wb, bb, gamma, var, fcw, beta, mean);

    final_kernel<<<1, 256, 0, stream>>>(fcb, bnfg, bnfb, bnfm, bnfv, (float*)d_out);
}

// Round 9
// 193.428 us; speedup vs baseline: 2.7259x; 1.0807x over previous
//
#include <hip/hip_runtime.h>
#include <stdint.h>

#define NUM_NODES 17185
#define DD 6
#define FEATS (NUM_NODES * DD)   // 103110
#define BATCH 256
#define EPS 1e-5f

#define NC 256   // nodes per block
#define NT 512   // threads: 2 row-groups x 256 nodes
#define BC 8     // batch rows per block total
#define RPH 4    // rows per half
#define NCHUNK ((NUM_NODES + NC - 1) / NC)   // 68

// Module-scope partials (d_ws unused; fills proved unconditional in R4).
__device__ float g_pm[NCHUNK * 256];
__device__ float g_pc[NCHUNK];

// R5/R6 lessons: no min-waves launch-bounds arg, no fused final tail (both spill).
// R9: row-split across 2 halves. acc[8]->acc[4] cuts live VGPR; data misses do
// not duplicate (halves read different rows); weight lines shared (MSHR-merged).
__global__ __launch_bounds__(NT) void main_kernel(
    const float* __restrict__ data, const float* __restrict__ wb, const float* __restrict__ bb,
    const float* __restrict__ gamma, const float* __restrict__ var, const float* __restrict__ fcw,
    const float* __restrict__ beta, const float* __restrict__ mean) {

    const int tid = threadIdx.x;
    const int nl  = tid & 255;          // node lane
    const int h   = tid >> 8;           // row-group half: rows h*4 .. h*4+3
    const int c   = blockIdx.x;
    const int n   = c * NC + nl;
    const bool valid = (n < NUM_NODES);

    float wreg[36], bias[6], a[6];
    #pragma unroll
    for (int k = 0; k < 36; k++) wreg[k] = 0.f;
    #pragma unroll
    for (int k = 0; k < 6; k++) { bias[k] = 0.f; a[k] = 0.f; }

    float cnode = 0.f;   // BN-constant contribution: h==0 threads of y==0 blocks only

    if (valid) {
        const float4* wp = (const float4*)(wb + (size_t)n * 36);   // 144B stride, 16-aligned
        #pragma unroll
        for (int k = 0; k < 9; k++) {
            float4 v = wp[k];
            wreg[4*k] = v.x; wreg[4*k+1] = v.y; wreg[4*k+2] = v.z; wreg[4*k+3] = v.w;
        }
        const float2* bp = (const float2*)(bb + (size_t)n * 6);
        #pragma unroll
        for (int k = 0; k < 3; k++) { float2 v = bp[k]; bias[2*k] = v.x; bias[2*k+1] = v.y; }
        const int f0 = n * 6;
        const float2* gp = (const float2*)(gamma + f0);
        const float2* vp = (const float2*)(var + f0);
        const float2* fp = (const float2*)(fcw + f0);
        float fw[6];
        #pragma unroll
        for (int k = 0; k < 3; k++) {
            float2 g = gp[k], v = vp[k], f = fp[k];
            fw[2*k] = f.x; fw[2*k+1] = f.y;
            a[2*k]   = g.x * rsqrtf(v.x + EPS) * f.x;
            a[2*k+1] = g.y * rsqrtf(v.y + EPS) * f.y;
        }
        if (h == 0 && blockIdx.y == 0) {
            const float2* bep = (const float2*)(beta + f0);
            const float2* mp  = (const float2*)(mean + f0);
            #pragma unroll
            for (int k = 0; k < 3; k++) {
                float2 be = bep[k], m = mp[k];
                cnode += be.x * fw[2*k]   - m.x * a[2*k];
                cnode += be.y * fw[2*k+1] - m.y * a[2*k+1];
            }
        }
    }

    const int b0 = blockIdx.y * BC + h * RPH;   // this half's first row
    float acc[RPH];
    #pragma unroll
    for (int r = 0; r < RPH; r++) acc[r] = 0.f;

    if (valid) {
        const float2* xbase = (const float2*)(data + (size_t)b0 * FEATS + (size_t)n * 6);
        #pragma unroll
        for (int r = 0; r < RPH; r++) {
            const float2* xp = xbase + (size_t)r * (FEATS / 2);
            float2 u0 = xp[0], u1 = xp[1], u2 = xp[2];
            float x0 = u0.x, x1 = u0.y, x2 = u1.x, x3 = u1.y, x4 = u2.x, x5 = u2.y;
            #pragma unroll
            for (int o = 0; o < 6; o++) {
                float s = bias[o];
                s = fmaf(x0, wreg[o*6+0], s);
                s = fmaf(x1, wreg[o*6+1], s);
                s = fmaf(x2, wreg[o*6+2], s);
                s = fmaf(x3, wreg[o*6+3], s);
                s = fmaf(x4, wreg[o*6+4], s);
                s = fmaf(x5, wreg[o*6+5], s);
                acc[r] = fmaf(fmaxf(s, 0.f), a[o], acc[r]);
            }
        }
    }

    // Reduction: 8 waves; waves 0-3 hold rows 0-3 (h=0), waves 4-7 hold rows 4-7.
    __shared__ float red[8][RPH];
    const int w = tid >> 6;
    #pragma unroll
    for (int r = 0; r < RPH; r++) {
        float v = acc[r];
        #pragma unroll
        for (int off = 32; off; off >>= 1) v += __shfl_down(v, off);
        if ((tid & 63) == 0) red[w][r] = v;
    }

    if (blockIdx.y == 0) {
        float v = cnode;   // 0 for h==1 threads
        #pragma unroll
        for (int off = 32; off; off >>= 1) v += __shfl_down(v, off);
        __shared__ float credd[8];
        if ((tid & 63) == 0) credd[w] = v;
        __syncthreads();
        if (tid == 0) {
            float s = 0.f;
            #pragma unroll
            for (int k = 0; k < 8; k++) s += credd[k];
            g_pc[c] = s;
        }
    } else {
        __syncthreads();
    }

    if (tid < BC) {
        const int q = tid;                  // row 0..7 within block
        const int wbase = (q < RPH) ? 0 : 4;
        const int r = q & (RPH - 1);
        float s = red[wbase + 0][r] + red[wbase + 1][r]
                + red[wbase + 2][r] + red[wbase + 3][r];
        g_pm[c * 256 + blockIdx.y * BC + q] = s;   // chunk-major
    }
}

__global__ __launch_bounds__(256) void final_kernel(
    const float* __restrict__ fcb, const float* __restrict__ bnfg,
    const float* __restrict__ bnfb, const float* __restrict__ bnfm,
    const float* __restrict__ bnfv, float* __restrict__ out) {
    const int b = threadIdx.x;

    float c = (b < NCHUNK) ? g_pc[b] : 0.f;
    #pragma unroll
    for (int off = 32; off; off >>= 1) c += __shfl_down(c, off);
    __shared__ float red[4];
    if ((b & 63) == 0) red[b >> 6] = c;
    __syncthreads();
    const float c_sum = red[0] + red[1] + red[2] + red[3];

    float y = 0.f;
    #pragma unroll 4
    for (int ch = 0; ch < NCHUNK; ch++) y += g_pm[ch * 256 + b];   // coalesced

    y += c_sum + fcb[0];
    float sc = bnfg[0] * rsqrtf(bnfv[0] + EPS);
    float z = (y - bnfm[0]) * sc + bnfb[0];
    out[b] = 1.f / (1.f + expf(-z));
}

extern "C" void kernel_launch(void* const* d_in, const int* in_sizes, int n_in,
                              void* d_out, int out_size, void* d_ws, size_t ws_size,
                              hipStream_t stream) {
    const float* data  = (const float*)d_in[0];
    const float* wb    = (const float*)d_in[1];
    const float* bb    = (const float*)d_in[2];
    const float* gamma = (const float*)d_in[3];
    const float* beta  = (const float*)d_in[4];
    const float* mean  = (const float*)d_in[5];
    const float* var   = (const float*)d_in[6];
    const float* fcw   = (const float*)d_in[7];
    const float* fcb   = (const float*)d_in[8];
    const float* bnfg  = (const float*)d_in[9];
    const float* bnfb  = (const float*)d_in[10];
    const float* bnfm  = (const float*)d_in[11];
    const float* bnfv  = (const float*)d_in[12];
    (void)d_ws; (void)ws_size;   // workspace intentionally unused (fills are unconditional)

    dim3 grid(NCHUNK, BATCH / BC);            // (68, 32) = 2176 blocks, 512 threads
    main_kernel<<<grid, NT, 0, stream>>>(data, wb, bb, gamma, var, fcw, beta, mean);

    final_kernel<<<1, 256, 0, stream>>>(fcb, bnfg, bnfb, bnfm, bnfv, (float*)d_out);
}